// Round 1
// baseline (655.062 us; speedup 1.0000x reference)
//
#include <hip/hip_runtime.h>
#include <hip/hip_bf16.h>

// Problem constants (from reference)
constexpr int N_NODES = 50000;
constexpr int N_EDGES = 800000;
constexpr int EN      = N_EDGES + N_NODES;   // edges + self loops
constexpr int HEADS   = 4;
constexpr int OUT_CH  = 32;
constexpr int HC      = HEADS * OUT_CH;      // 128
constexpr float NEG_SLOPE = 0.2f;
constexpr float EPS_LN    = 1e-5f;

// ---------- order-preserving float<->uint encoding for atomicMax ----------
__device__ __forceinline__ unsigned enc_f32(float f) {
    unsigned u = __float_as_uint(f);
    return (u & 0x80000000u) ? ~u : (u | 0x80000000u);
}
__device__ __forceinline__ float dec_f32(unsigned k) {
    unsigned u = (k & 0x80000000u) ? (k ^ 0x80000000u) : ~k;
    return __uint_as_float(u);
}

// ---------- Kernel 1: h = x @ W  (+ per-node attention dots) ----------
// block = 128 threads (thread t owns output channel t), W staged in LDS (64KB),
// 8 rows per batch staged in LDS, float4 broadcast reads on the k-loop.
__global__ __launch_bounds__(128)
void gemm_att(const float* __restrict__ x, const float* __restrict__ W,
              const float* __restrict__ att_s, const float* __restrict__ att_d,
              float* __restrict__ h, float* __restrict__ asrc, float* __restrict__ adst) {
    __shared__ float Wl[HC * HC];        // 64 KB
    __shared__ float xs[8][HC];          // 4 KB
    const int t = threadIdx.x;           // 0..127
    for (int i = t; i < HC * HC; i += 128) Wl[i] = W[i];
    const float as = att_s[t];
    const float ad = att_d[t];
    const int lane = t & 63;
    const int head = t >> 5;

    for (int row0 = blockIdx.x * 8; row0 < N_NODES; row0 += gridDim.x * 8) {
        __syncthreads();                 // protect xs readers of previous batch (and Wl stage)
        #pragma unroll
        for (int r = 0; r < 8; ++r)
            xs[r][t] = x[(size_t)(row0 + r) * HC + t];
        __syncthreads();

        float acc[8];
        #pragma unroll
        for (int r = 0; r < 8; ++r) acc[r] = 0.f;

        for (int k = 0; k < HC; k += 4) {
            const float w0 = Wl[(k + 0) * HC + t];
            const float w1 = Wl[(k + 1) * HC + t];
            const float w2 = Wl[(k + 2) * HC + t];
            const float w3 = Wl[(k + 3) * HC + t];
            #pragma unroll
            for (int r = 0; r < 8; ++r) {
                const float4 xv = *(const float4*)&xs[r][k];  // broadcast, conflict-free
                acc[r] += w0 * xv.x + w1 * xv.y + w2 * xv.z + w3 * xv.w;
            }
        }

        #pragma unroll
        for (int r = 0; r < 8; ++r) {
            h[(size_t)(row0 + r) * HC + t] = acc[r];
            float vs = acc[r] * as;
            float vd = acc[r] * ad;
            #pragma unroll
            for (int s = 16; s >= 1; s >>= 1) {   // reduce within 32-lane head group
                vs += __shfl_xor(vs, s, 64);
                vd += __shfl_xor(vd, s, 64);
            }
            if ((lane & 31) == 0) {
                asrc[(row0 + r) * HEADS + head] = vs;
                adst[(row0 + r) * HEADS + head] = vd;
            }
        }
    }
}

// ---------- Kernel 2: per-(edge,head) leaky_relu logit + segment max ----------
__global__ __launch_bounds__(256)
void edge_max(const int* __restrict__ ei, const float* __restrict__ asrc,
              const float* __restrict__ adst, float* __restrict__ p,
              unsigned* __restrict__ menc) {
    const int idx = blockIdx.x * 256 + threadIdx.x;
    if (idx >= EN * HEADS) return;
    const int e = idx >> 2;
    const int hh = idx & 3;
    const int src = (e < N_EDGES) ? ei[e] : (e - N_EDGES);
    const int dst = (e < N_EDGES) ? ei[N_EDGES + e] : (e - N_EDGES);
    float v = asrc[src * HEADS + hh] + adst[dst * HEADS + hh];
    v = (v > 0.f) ? v : NEG_SLOPE * v;
    p[idx] = v;
    atomicMax(&menc[dst * HEADS + hh], enc_f32(v));
}

// ---------- Kernel 3: exp(e - m[dst]) + segment sum ----------
__global__ __launch_bounds__(256)
void edge_exp(const int* __restrict__ ei, const unsigned* __restrict__ menc,
              float* __restrict__ p, float* __restrict__ den) {
    const int idx = blockIdx.x * 256 + threadIdx.x;
    if (idx >= EN * HEADS) return;
    const int e = idx >> 2;
    const int hh = idx & 3;
    const int dst = (e < N_EDGES) ? ei[N_EDGES + e] : (e - N_EDGES);
    const float m = dec_f32(menc[dst * HEADS + hh]);
    const float pv = expf(p[idx] - m);
    p[idx] = pv;
    atomicAdd(&den[dst * HEADS + hh], pv);
}

// ---------- Kernel 4: alpha = p / (denom[dst] + 1e-16) ----------
__global__ __launch_bounds__(256)
void edge_alpha(const int* __restrict__ ei, const float* __restrict__ den,
                float* __restrict__ p) {
    const int idx = blockIdx.x * 256 + threadIdx.x;
    if (idx >= EN * HEADS) return;
    const int e = idx >> 2;
    const int hh = idx & 3;
    const int dst = (e < N_EDGES) ? ei[N_EDGES + e] : (e - N_EDGES);
    p[idx] = p[idx] / (den[dst * HEADS + hh] + 1e-16f);
}

// ---------- Kernel 5: scatter-aggregate messages (the elephant) ----------
// thread per (edge, channel); 128 consecutive threads share one edge.
__global__ __launch_bounds__(256)
void scatter_msg(const int* __restrict__ ei, const float* __restrict__ p,
                 const float* __restrict__ hbuf, float* __restrict__ out) {
    const int gid = blockIdx.x * 256 + threadIdx.x;   // < 108.8M, fits int32
    const int e = gid >> 7;
    const int c = gid & 127;
    const int hh = c >> 5;
    const int src = (e < N_EDGES) ? ei[e] : (e - N_EDGES);
    const int dst = (e < N_EDGES) ? ei[N_EDGES + e] : (e - N_EDGES);
    const float alpha = p[e * HEADS + hh];
    const float val = alpha * hbuf[(size_t)src * HC + c];
    atomicAdd(&out[(size_t)dst * HC + c], val);
}

// ---------- Kernel 6: bias + ELU + residual + LayerNorm ----------
// one 64-lane wave per node; lane l owns channels l and l+64.
__global__ __launch_bounds__(256)
void epilogue(float* __restrict__ out, const float* __restrict__ x,
              const float* __restrict__ bias, const float* __restrict__ gamma,
              const float* __restrict__ beta) {
    const int wave = threadIdx.x >> 6;
    const int lane = threadIdx.x & 63;
    const int n = blockIdx.x * 4 + wave;
    if (n >= N_NODES) return;
    const size_t base = (size_t)n * HC;

    float v0 = out[base + lane]      + bias[lane];
    float v1 = out[base + lane + 64] + bias[lane + 64];
    v0 = (v0 > 0.f) ? v0 : expm1f(v0);
    v1 = (v1 > 0.f) ? v1 : expm1f(v1);
    v0 += x[base + lane];
    v1 += x[base + lane + 64];

    float s  = v0 + v1;
    float sq = v0 * v0 + v1 * v1;
    #pragma unroll
    for (int m = 32; m >= 1; m >>= 1) {
        s  += __shfl_xor(s,  m, 64);
        sq += __shfl_xor(sq, m, 64);
    }
    const float mu   = s * (1.f / HC);
    const float var  = sq * (1.f / HC) - mu * mu;
    const float rstd = rsqrtf(var + EPS_LN);

    out[base + lane]      = (v0 - mu) * rstd * gamma[lane]      + beta[lane];
    out[base + lane + 64] = (v1 - mu) * rstd * gamma[lane + 64] + beta[lane + 64];
}

extern "C" void kernel_launch(void* const* d_in, const int* in_sizes, int n_in,
                              void* d_out, int out_size, void* d_ws, size_t ws_size,
                              hipStream_t stream) {
    const float* x     = (const float*)d_in[0];
    const int*   ei    = (const int*)  d_in[1];   // JAX default: int64 demoted to int32
    const float* W     = (const float*)d_in[2];
    const float* att_s = (const float*)d_in[3];
    const float* att_d = (const float*)d_in[4];
    const float* bias  = (const float*)d_in[5];
    const float* gamma = (const float*)d_in[6];
    const float* beta  = (const float*)d_in[7];
    float* out = (float*)d_out;

    // workspace layout (bytes, all 256-aligned)
    char* ws = (char*)d_ws;
    float*    h    = (float*)   (ws);              // 50000*128*4 = 25,600,000
    float*    asrc = (float*)   (ws + 25600000);   //   800,000
    float*    adst = (float*)   (ws + 26400000);   //   800,000
    unsigned* menc = (unsigned*)(ws + 27200000);   //   800,000
    float*    den  = (float*)   (ws + 28000000);   //   800,000
    float*    p    = (float*)   (ws + 28800000);   // 850000*4*4 = 13,600,000  (total 42.4 MB)

    hipMemsetAsync(menc, 0, (size_t)N_NODES * HEADS * 4, stream);  // encoded -inf
    hipMemsetAsync(den,  0, (size_t)N_NODES * HEADS * 4, stream);
    hipMemsetAsync(out,  0, (size_t)N_NODES * HC * 4, stream);

    gemm_att<<<512, 128, 0, stream>>>(x, W, att_s, att_d, h, asrc, adst);

    const int eh_grid = (EN * HEADS + 255) / 256;
    edge_max  <<<eh_grid, 256, 0, stream>>>(ei, asrc, adst, p, menc);
    edge_exp  <<<eh_grid, 256, 0, stream>>>(ei, menc, p, den);
    edge_alpha<<<eh_grid, 256, 0, stream>>>(ei, den, p);

    scatter_msg<<<(EN * HC) / 256, 256, 0, stream>>>(ei, p, h, out);  // 425,000 blocks

    epilogue<<<(N_NODES + 3) / 4, 256, 0, stream>>>(out, x, bias, gamma, beta);
}

// Round 3
// 412.415 us; speedup vs baseline: 1.5884x; 1.5884x over previous
//
#include <hip/hip_runtime.h>
#include <hip/hip_bf16.h>

// Problem constants (from reference)
constexpr int N_NODES = 50000;
constexpr int N_EDGES = 800000;
constexpr int EN      = N_EDGES + N_NODES;   // edges + self loops
constexpr int HEADS   = 4;
constexpr int OUT_CH  = 32;
constexpr int HC      = HEADS * OUT_CH;      // 128
constexpr float NEG_SLOPE = 0.2f;
constexpr float EPS_LN    = 1e-5f;

// ---------- Kernel 1: h = x @ W  (+ per-node attention dots) ----------
// block = 128 threads (thread t owns output channel t), W staged in LDS (64KB),
// 8 rows per batch staged in LDS, float4 broadcast reads on the k-loop.
__global__ __launch_bounds__(128)
void gemm_att(const float* __restrict__ x, const float* __restrict__ W,
              const float* __restrict__ att_s, const float* __restrict__ att_d,
              float* __restrict__ h, float* __restrict__ asrc, float* __restrict__ adst) {
    __shared__ float Wl[HC * HC];        // 64 KB
    __shared__ float xs[8][HC];          // 4 KB
    const int t = threadIdx.x;           // 0..127
    for (int i = t; i < HC * HC; i += 128) Wl[i] = W[i];
    const float as = att_s[t];
    const float ad = att_d[t];
    const int lane = t & 63;
    const int head = t >> 5;

    for (int row0 = blockIdx.x * 8; row0 < N_NODES; row0 += gridDim.x * 8) {
        __syncthreads();                 // protect xs readers of previous batch (and Wl stage)
        #pragma unroll
        for (int r = 0; r < 8; ++r)
            xs[r][t] = x[(size_t)(row0 + r) * HC + t];
        __syncthreads();

        float acc[8];
        #pragma unroll
        for (int r = 0; r < 8; ++r) acc[r] = 0.f;

        for (int k = 0; k < HC; k += 4) {
            const float w0 = Wl[(k + 0) * HC + t];
            const float w1 = Wl[(k + 1) * HC + t];
            const float w2 = Wl[(k + 2) * HC + t];
            const float w3 = Wl[(k + 3) * HC + t];
            #pragma unroll
            for (int r = 0; r < 8; ++r) {
                const float4 xv = *(const float4*)&xs[r][k];  // broadcast, conflict-free
                acc[r] += w0 * xv.x + w1 * xv.y + w2 * xv.z + w3 * xv.w;
            }
        }

        #pragma unroll
        for (int r = 0; r < 8; ++r) {
            h[(size_t)(row0 + r) * HC + t] = acc[r];
            float vs = acc[r] * as;
            float vd = acc[r] * ad;
            #pragma unroll
            for (int s = 16; s >= 1; s >>= 1) {   // reduce within 32-lane head group
                vs += __shfl_xor(vs, s, 64);
                vd += __shfl_xor(vd, s, 64);
            }
            if ((lane & 31) == 0) {
                asrc[(row0 + r) * HEADS + head] = vs;
                adst[(row0 + r) * HEADS + head] = vd;
            }
        }
    }
}

// ---------- Kernel 2: histogram of in-degrees (incl. self loops) ----------
__global__ __launch_bounds__(256)
void deg_hist(const int* __restrict__ ei, unsigned* __restrict__ deg) {
    const int e = blockIdx.x * 256 + threadIdx.x;
    if (e >= EN) return;
    const int dst = (e < N_EDGES) ? ei[N_EDGES + e] : (e - N_EDGES);
    atomicAdd(&deg[dst], 1u);
}

// ---------- Kernel 3: exclusive scan of deg -> row_start (single block) ----------
__global__ __launch_bounds__(1024)
void scan_rows(const unsigned* __restrict__ deg, unsigned* __restrict__ rs) {
    __shared__ unsigned wsum[16];
    const int tid = threadIdx.x, lane = tid & 63, w = tid >> 6;
    unsigned carry = 0;                          // uniform across threads
    for (int base = 0; base < N_NODES; base += 1024) {
        const int i = base + tid;
        const unsigned v = (i < N_NODES) ? deg[i] : 0u;
        unsigned incl = v;
        #pragma unroll
        for (int off = 1; off < 64; off <<= 1) {
            const unsigned nb = __shfl_up(incl, off, 64);
            if (lane >= off) incl += nb;
        }
        if (lane == 63) wsum[w] = incl;
        __syncthreads();
        unsigned woff = 0, total = 0;
        #pragma unroll
        for (int j = 0; j < 16; ++j) {
            if (j < w) woff += wsum[j];
            total += wsum[j];
        }
        if (i < N_NODES) rs[i] = carry + woff + incl - v;   // exclusive
        carry += total;
        __syncthreads();                          // protect wsum for next chunk
    }
    if (tid == 0) rs[N_NODES] = carry;            // == EN
}

// ---------- Kernel 4: scatter edges into CSR order (store src only) ----------
__global__ __launch_bounds__(256)
void scatter_edges(const int* __restrict__ ei, const unsigned* __restrict__ rs,
                   unsigned* __restrict__ cursor, int* __restrict__ esrc) {
    const int e = blockIdx.x * 256 + threadIdx.x;
    if (e >= EN) return;
    const int src = (e < N_EDGES) ? ei[e] : (e - N_EDGES);
    const int dst = (e < N_EDGES) ? ei[N_EDGES + e] : (e - N_EDGES);
    const unsigned pos = rs[dst] + atomicAdd(&cursor[dst], 1u);
    esrc[pos] = src;
}

// ---------- Kernel 5: fused per-node online-softmax aggregate + epilogue ----------
// one 128-thread block per dst node; thread t owns channel t (head = t>>5).
// Online softmax over incoming edges: running max m, sum s, rescaled acc.
__global__ __launch_bounds__(128)
void gat_aggregate(const int* __restrict__ esrc, const unsigned* __restrict__ rs,
                   const float* __restrict__ asrc, const float* __restrict__ adst,
                   const float* __restrict__ h, const float* __restrict__ x,
                   const float* __restrict__ bias, const float* __restrict__ gamma,
                   const float* __restrict__ beta, float* __restrict__ out) {
    const int n = blockIdx.x;
    const int t = threadIdx.x;
    const int hh = t >> 5;
    const int start = (int)rs[n], end = (int)rs[n + 1];
    const float adn = adst[n * HEADS + hh];

    float m = -INFINITY, s = 0.f, acc = 0.f;
    int pos = start;
    // 2-edge unrolled online softmax (helps ILP / hides gather latency)
    for (; pos + 1 < end; pos += 2) {
        const int s0 = esrc[pos], s1 = esrc[pos + 1];
        float v0 = asrc[s0 * HEADS + hh] + adn;
        float v1 = asrc[s1 * HEADS + hh] + adn;
        v0 = (v0 > 0.f) ? v0 : NEG_SLOPE * v0;
        v1 = (v1 > 0.f) ? v1 : NEG_SLOPE * v1;
        const float h0 = h[(size_t)s0 * HC + t];
        const float h1 = h[(size_t)s1 * HC + t];
        const float nm = fmaxf(m, fmaxf(v0, v1));
        const float c  = expf(m - nm);           // 0 when m == -inf
        const float w0 = expf(v0 - nm);
        const float w1 = expf(v1 - nm);
        acc = acc * c + w0 * h0 + w1 * h1;
        s   = s   * c + w0 + w1;
        m = nm;
    }
    if (pos < end) {
        const int s0 = esrc[pos];
        float v0 = asrc[s0 * HEADS + hh] + adn;
        v0 = (v0 > 0.f) ? v0 : NEG_SLOPE * v0;
        const float h0 = h[(size_t)s0 * HC + t];
        const float nm = fmaxf(m, v0);
        const float c  = expf(m - nm);
        const float w0 = expf(v0 - nm);
        acc = acc * c + w0 * h0;
        s   = s   * c + w0;
    }

    // epilogue: bias + ELU + residual + LayerNorm over the 128 channels
    float o = acc / (s + 1e-16f) + bias[t];
    o = (o > 0.f) ? o : expm1f(o);
    o += x[(size_t)n * HC + t];

    __shared__ float red[4];
    float ss = o, sq = o * o;
    #pragma unroll
    for (int off = 32; off >= 1; off >>= 1) {
        ss += __shfl_xor(ss, off, 64);
        sq += __shfl_xor(sq, off, 64);
    }
    const int w = t >> 6;
    if ((t & 63) == 0) { red[w * 2] = ss; red[w * 2 + 1] = sq; }
    __syncthreads();
    const float S = red[0] + red[2], Q = red[1] + red[3];
    const float mu   = S * (1.f / HC);
    const float var  = Q * (1.f / HC) - mu * mu;
    const float rstd = rsqrtf(var + EPS_LN);
    out[(size_t)n * HC + t] = (o - mu) * rstd * gamma[t] + beta[t];
}

extern "C" void kernel_launch(void* const* d_in, const int* in_sizes, int n_in,
                              void* d_out, int out_size, void* d_ws, size_t ws_size,
                              hipStream_t stream) {
    const float* x     = (const float*)d_in[0];
    const int*   ei    = (const int*)  d_in[1];
    const float* W     = (const float*)d_in[2];
    const float* att_s = (const float*)d_in[3];
    const float* att_d = (const float*)d_in[4];
    const float* bias  = (const float*)d_in[5];
    const float* gamma = (const float*)d_in[6];
    const float* beta  = (const float*)d_in[7];
    float* out = (float*)d_out;

    // workspace layout (bytes, 256-aligned)
    char* ws = (char*)d_ws;
    float*    h      = (float*)   (ws);              // 25,600,000
    float*    asrc   = (float*)   (ws + 25600000);   //    800,000
    float*    adst   = (float*)   (ws + 26400000);   //    800,000
    unsigned* deg    = (unsigned*)(ws + 27200000);   //    200,000
    unsigned* cursor = (unsigned*)(ws + 27400000);   //    200,000
    unsigned* rs     = (unsigned*)(ws + 27600000);   //    200,004 (N+1)
    int*      esrc   = (int*)     (ws + 27800192);   //  3,400,000  (total ~31.2 MB)

    hipMemsetAsync(deg,    0, (size_t)N_NODES * 4, stream);
    hipMemsetAsync(cursor, 0, (size_t)N_NODES * 4, stream);

    gemm_att<<<512, 128, 0, stream>>>(x, W, att_s, att_d, h, asrc, adst);

    const int e_grid = (EN + 255) / 256;
    deg_hist     <<<e_grid, 256, 0, stream>>>(ei, deg);
    scan_rows    <<<1, 1024, 0, stream>>>(deg, rs);
    scatter_edges<<<e_grid, 256, 0, stream>>>(ei, rs, cursor, esrc);

    gat_aggregate<<<N_NODES, 128, 0, stream>>>(esrc, rs, asrc, adst, h, x,
                                               bias, gamma, beta, out);
}